// Round 2
// baseline (239.075 us; speedup 1.0000x reference)
//
#include <hip/hip_runtime.h>
#include <math.h>

#define NN 50000
#define NE 600000
#define CIN 128
#define GR 64

// ---------------- kernel 1: count in-degree over targets ----------------------
__global__ void k_count(const int* __restrict__ ei, int* __restrict__ cnt) {
    int e = blockIdx.x * blockDim.x + threadIdx.x;
    if (e >= NE) return;
    atomicAdd(&cnt[ei[NE + e]], 1);   // target i
}

// ---------------- kernel 2: dinv = rsqrt(deg), deg includes self loop ---------
__global__ void k_dinv(const int* __restrict__ cnt, float* __restrict__ dinv) {
    int i = blockIdx.x * blockDim.x + threadIdx.x;
    if (i < NN) dinv[i] = rsqrtf((float)(cnt[i] + 1));
}

// ---------------- kernel 3: exclusive prefix scan of cnt (single block) -------
__global__ __launch_bounds__(1024) void k_scan(const int* __restrict__ cnt,
                                               int* __restrict__ off,
                                               int* __restrict__ cursor) {
    __shared__ int wsum[16];
    __shared__ int carry_s;
    int tid = threadIdx.x;
    int lane = tid & 63, wid = tid >> 6;
    if (tid == 0) carry_s = 0;
    __syncthreads();
    for (int base = 0; base < NN; base += 1024) {
        int i = base + tid;
        int v = (i < NN) ? cnt[i] : 0;
        int s = v;
#pragma unroll
        for (int d = 1; d < 64; d <<= 1) {
            int t = __shfl_up(s, d, 64);
            if (lane >= d) s += t;
        }
        if (lane == 63) wsum[wid] = s;
        __syncthreads();
        int carry = carry_s;
        int wexcl = 0;
#pragma unroll
        for (int w = 0; w < 16; ++w) if (w < wid) wexcl += wsum[w];
        int excl = carry + wexcl + (s - v);
        if (i < NN) { off[i] = excl; cursor[i] = excl; }
        __syncthreads();
        if (tid == 0) {
            int tot = 0;
#pragma unroll
            for (int w = 0; w < 16; ++w) tot += wsum[w];
            carry_s = carry + tot;
        }
        __syncthreads();
    }
}

// ---------------- kernel 4: fill CSR edge list (source per slot) --------------
__global__ void k_fill(const int* __restrict__ ei, int* __restrict__ cursor,
                       int* __restrict__ eidx) {
    int e = blockIdx.x * blockDim.x + threadIdx.x;
    if (e >= NE) return;
    int r = ei[e];                     // source j
    int c = ei[NE + e];                // target i
    int slot = atomicAdd(&cursor[c], 1);
    eidx[slot] = r;
}

// ---------------- kernel 5: pull-aggregation in x-space -----------------------
// s[i] = dinv_i^2 * ( sum_{e: col=i} x[r]*dinv[r] + dinv_i*x[i] ). Writes d_out.
__global__ __launch_bounds__(256) void k_agg(const float* __restrict__ x,
                                             const int* __restrict__ cnt,
                                             const int* __restrict__ off,
                                             const int* __restrict__ eidx,
                                             const float* __restrict__ dinv,
                                             float* __restrict__ out) {
    int node = blockIdx.x * 4 + (threadIdx.x >> 6);
    if (node >= NN) return;
    int lane = threadIdx.x & 63;
    const float2* x2 = (const float2*)x;
    float ax = 0.f, ay = 0.f;
    int n = cnt[node];
    int start = off[node];
    float di = dinv[node];
    for (int k = 0; k < n; ++k) {
        int r = eidx[start + k];       // wave-uniform
        float w = dinv[r];             // wave-uniform
        float2 v = x2[r * 64 + lane];  // coalesced 512B gather
        ax = fmaf(v.x, w, ax);
        ay = fmaf(v.y, w, ay);
    }
    float2 xs = x2[node * 64 + lane];
    ax = fmaf(xs.x, di, ax);
    ay = fmaf(xs.y, di, ay);
    float sc = di * di;
    float2 o;
    o.x = ax * sc;
    o.y = ay * sc;
    ((float2*)out)[node * 64 + lane] = o;
}

// ---------------- kernel 6: in-place GEMM (s @ W^T) + bias + SiLU -------------
// Block: 64 rows, 512 threads, 4x4 microtile per thread.
// W stored transposed in LDS with stride 132 floats -> conflict-free b128 reads.
__global__ __launch_bounds__(512) void k_gemm_silu(float* __restrict__ io,
                                                   const float* __restrict__ Wg,
                                                   const float* __restrict__ bg) {
    __shared__ float s_s[GR * CIN];      // 32 KB: input rows
    __shared__ float s_w[CIN * 132];     // 66 KB: W transposed [c][o], stride 132
    int tid = threadIdx.x;
    int row0 = blockIdx.x * GR;

    // load this block's rows of s (guarded, zero-pad OOB)
    {
        const float4* g4 = (const float4*)io;
        float4* l4 = (float4*)s_s;
        int base4 = row0 * (CIN / 4);
        int lim4 = NN * (CIN / 4);
#pragma unroll
        for (int k = 0; k < (GR * CIN / 4) / 512; ++k) {  // 4 iters
            int idx = tid + 512 * k;
            float4 v = make_float4(0.f, 0.f, 0.f, 0.f);
            if (base4 + idx < lim4) v = g4[base4 + idx];
            l4[idx] = v;
        }
    }
    // load W transposed: Wg is [o][c] row-major, 128x128
    {
        const float4* w4 = (const float4*)Wg;
#pragma unroll
        for (int k = 0; k < 8; ++k) {
            int f = tid + 512 * k;        // float4 index 0..4095
            float4 v = w4[f];
            int o = f >> 5;               // 0..127
            int c0 = (f & 31) * 4;        // 0..124
            s_w[(c0 + 0) * 132 + o] = v.x;
            s_w[(c0 + 1) * 132 + o] = v.y;
            s_w[(c0 + 2) * 132 + o] = v.z;
            s_w[(c0 + 3) * 132 + o] = v.w;
        }
    }
    __syncthreads();

    int ct = tid & 31;   // output col group: o0 = ct*4 (lanes contiguous -> conflict-free)
    int rt = tid >> 5;   // 0..15: row group r0 = rt*4 (broadcast s reads)
    float acc[4][4];
#pragma unroll
    for (int i = 0; i < 4; ++i) {
        acc[i][0] = 0.f; acc[i][1] = 0.f; acc[i][2] = 0.f; acc[i][3] = 0.f;
    }

    for (int c = 0; c < CIN; c += 4) {
        float sv[4][4];
#pragma unroll
        for (int i = 0; i < 4; ++i) {
            float4 t = *(const float4*)&s_s[(rt * 4 + i) * CIN + c];
            sv[i][0] = t.x; sv[i][1] = t.y; sv[i][2] = t.z; sv[i][3] = t.w;
        }
#pragma unroll
        for (int k = 0; k < 4; ++k) {
            float4 wv = *(const float4*)&s_w[(c + k) * 132 + ct * 4];
#pragma unroll
            for (int i = 0; i < 4; ++i) {
                acc[i][0] = fmaf(sv[i][k], wv.x, acc[i][0]);
                acc[i][1] = fmaf(sv[i][k], wv.y, acc[i][1]);
                acc[i][2] = fmaf(sv[i][k], wv.z, acc[i][2]);
                acc[i][3] = fmaf(sv[i][k], wv.w, acc[i][3]);
            }
        }
    }

    // epilogue: bias + silu, write back in place (rows are block-private)
    float4 bv = *(const float4*)&bg[ct * 4];
#pragma unroll
    for (int i = 0; i < 4; ++i) {
        int r = row0 + rt * 4 + i;
        if (r < NN) {
            float4 v;
            v.x = acc[i][0] + bv.x;
            v.y = acc[i][1] + bv.y;
            v.z = acc[i][2] + bv.z;
            v.w = acc[i][3] + bv.w;
            v.x = v.x / (1.f + __expf(-v.x));
            v.y = v.y / (1.f + __expf(-v.y));
            v.z = v.z / (1.f + __expf(-v.z));
            v.w = v.w / (1.f + __expf(-v.w));
            *(float4*)&io[r * CIN + ct * 4] = v;
        }
    }
}

extern "C" void kernel_launch(void* const* d_in, const int* in_sizes, int n_in,
                              void* d_out, int out_size, void* d_ws, size_t ws_size,
                              hipStream_t stream) {
    const float* x = (const float*)d_in[0];
    const int* ei = (const int*)d_in[1];   // int32 per harness convention
    const float* W = (const float*)d_in[2];
    const float* b = (const float*)d_in[3];
    float* out = (float*)d_out;

    // workspace layout (~3.2 MB total)
    char* w = (char*)d_ws;
    int*   cnt    = (int*)(w);              // 50000 ints
    float* dinv   = (float*)(w + 204800);   // 50000 floats
    int*   off    = (int*)(w + 409600);     // 50000 ints
    int*   cursor = (int*)(w + 614400);     // 50000 ints
    int*   eidx   = (int*)(w + 819200);     // 600000 ints (2.4 MB)

    hipMemsetAsync(cnt, 0, NN * sizeof(int), stream);

    k_count<<<(NE + 255) / 256, 256, 0, stream>>>(ei, cnt);
    k_dinv<<<(NN + 255) / 256, 256, 0, stream>>>(cnt, dinv);
    k_scan<<<1, 1024, 0, stream>>>(cnt, off, cursor);
    k_fill<<<(NE + 255) / 256, 256, 0, stream>>>(ei, cursor, eidx);
    k_agg<<<(NN + 3) / 4, 256, 0, stream>>>(x, cnt, off, eidx, dinv, out);
    k_gemm_silu<<<(NN + GR - 1) / GR, 512, 0, stream>>>(out, W, b);
}